// Round 1
// 54533.728 us; speedup vs baseline: 19.8588x; 19.8588x over previous
//
#include <hip/hip_runtime.h>
#include <hip/hip_bf16.h>
#include <vector>
#include <array>
#include <cmath>
#include <cstring>

// ============================================================================
// Host-side CG tensor construction (replicates the numpy reference, fp64).
// numpy.linalg.svd -> dgesdd; for our Laplacian shape (1x6) the null-space
// rows vh[rank:] equal the bottom (n-m) rows of Q from dgelqf (full row
// rank). We replicate dgelqf/dlarfg/dorglq exactly.
// ============================================================================
namespace cgh {

struct DMat {
  int r = 0, c = 0;
  std::vector<double> a;
  DMat() {}
  DMat(int r_, int c_) : r(r_), c(c_), a((size_t)r_ * c_, 0.0) {}
  double& at(int i, int j) { return a[(size_t)i * c + j]; }
  double at(int i, int j) const { return a[(size_t)i * c + j]; }
};

static std::vector<std::array<int, 3>> counts_list(int L) {
  std::vector<std::array<int, 3>> v;
  for (int a = L; a >= 0; a--)
    for (int b = L - a; b >= 0; b--)
      v.push_back({a, b, L - a - b});
  return v;
}

static double dfact(int n) { double o = 1; for (int k = n; k > 0; k -= 2) o *= k; return o; }
static double gmom(int n) { return (n % 2) ? 0.0 : dfact(n - 1); }
static double fact(int n) { double o = 1; for (int i = 2; i <= n; i++) o *= i; return o; }

static DMat gram(int L) {
  auto cts = counts_list(L);
  int D = (int)cts.size();
  DMat G(D, D);
  for (int i = 0; i < D; i++)
    for (int j = 0; j < D; j++)
      G.at(i, j) = gmom(cts[i][0] + cts[j][0]) * gmom(cts[i][1] + cts[j][1]) *
                   gmom(cts[i][2] + cts[j][2]);
  return G;
}

static int find_idx(const std::vector<std::array<int, 3>>& cts, int a, int b, int c) {
  for (size_t i = 0; i < cts.size(); i++)
    if (cts[i][0] == a && cts[i][1] == b && cts[i][2] == c) return (int)i;
  return -1;
}

static DMat laplacian(int L) {
  auto ctsL = counts_list(L);
  auto ctsM = counts_list(L - 2);
  DMat D((int)ctsM.size(), (int)ctsL.size());
  for (size_t j = 0; j < ctsL.size(); j++) {
    int a = ctsL[j][0], b = ctsL[j][1], c = ctsL[j][2];
    if (a >= 2) D.at(find_idx(ctsM, a - 2, b, c), (int)j) += a * (a - 1);
    if (b >= 2) D.at(find_idx(ctsM, a, b - 2, c), (int)j) += b * (b - 1);
    if (c >= 2) D.at(find_idx(ctsM, a, b, c - 2), (int)j) += c * (c - 1);
  }
  return D;
}

// dgelqf + dorglq: bottom (n-m) rows of Q (= vh[rank:] for full-row-rank A)
static DMat lq_null(DMat A) {
  int m = A.r, n = A.c;
  std::vector<double> tau(m, 0.0);
  for (int i = 0; i < m; i++) {
    double xn2 = 0;
    for (int c2 = i + 1; c2 < n; c2++) xn2 += A.at(i, c2) * A.at(i, c2);
    double alpha = A.at(i, i);
    if (xn2 == 0.0) { tau[i] = 0.0; continue; }
    double nrm = std::sqrt(alpha * alpha + xn2);
    double beta = (alpha >= 0.0) ? -nrm : nrm;
    tau[i] = (beta - alpha) / beta;
    double sc = 1.0 / (alpha - beta);
    for (int c2 = i + 1; c2 < n; c2++) A.at(i, c2) *= sc;
    A.at(i, i) = beta;
    for (int r2 = i + 1; r2 < m; r2++) {
      double w = A.at(r2, i);
      for (int c2 = i + 1; c2 < n; c2++) w += A.at(r2, c2) * A.at(i, c2);
      w *= tau[i];
      A.at(r2, i) -= w;
      for (int c2 = i + 1; c2 < n; c2++) A.at(r2, c2) -= w * A.at(i, c2);
    }
  }
  DMat Q(n, n);
  for (int i = 0; i < n; i++) Q.at(i, i) = 1.0;
  for (int i = 0; i < m; i++) {
    if (tau[i] == 0.0) continue;
    std::vector<double> v(n, 0.0);
    v[i] = 1.0;
    for (int c2 = i + 1; c2 < n; c2++) v[c2] = A.at(i, c2);
    for (int c2 = 0; c2 < n; c2++) {
      double s = 0;
      for (int r2 = i; r2 < n; r2++) s += v[r2] * Q.at(r2, c2);
      s *= tau[i];
      for (int r2 = i; r2 < n; r2++) Q.at(r2, c2) -= v[r2] * s;
    }
  }
  DMat Nl(n - m, n);
  for (int r2 = 0; r2 < n - m; r2++)
    for (int c2 = 0; c2 < n; c2++) Nl.at(r2, c2) = Q.at(m + r2, c2);
  return Nl;
}

static DMat matmul(const DMat& A, const DMat& B) {
  DMat C(A.r, B.c);
  for (int i = 0; i < A.r; i++)
    for (int k = 0; k < A.c; k++) {
      double av = A.at(i, k);
      if (av == 0.0) continue;
      for (int j = 0; j < B.c; j++) C.at(i, j) += av * B.at(k, j);
    }
  return C;
}
static DMat transpose(const DMat& A) {
  DMat T(A.c, A.r);
  for (int i = 0; i < A.r; i++)
    for (int j = 0; j < A.c; j++) T.at(j, i) = A.at(i, j);
  return T;
}

static void eigh_sym(DMat A, std::vector<double>& w, DMat& V) {
  int n = A.r;
  V = DMat(n, n);
  for (int i = 0; i < n; i++) V.at(i, i) = 1.0;
  for (int sweep = 0; sweep < 200; sweep++) {
    double off = 0;
    for (int p = 0; p < n - 1; p++)
      for (int q = p + 1; q < n; q++) off += A.at(p, q) * A.at(p, q);
    if (off < 1e-28) break;
    for (int p = 0; p < n - 1; p++)
      for (int q = p + 1; q < n; q++) {
        double apq = A.at(p, q);
        if (std::fabs(apq) < 1e-300) continue;
        double app = A.at(p, p), aqq = A.at(q, q);
        double th = (aqq - app) / (2.0 * apq);
        double t = (th >= 0) ? 1.0 / (th + std::sqrt(1.0 + th * th))
                             : 1.0 / (th - std::sqrt(1.0 + th * th));
        double c = 1.0 / std::sqrt(1.0 + t * t), s = t * c;
        for (int i = 0; i < n; i++) {
          double aip = A.at(i, p), aiq = A.at(i, q);
          A.at(i, p) = c * aip - s * aiq;
          A.at(i, q) = s * aip + c * aiq;
        }
        for (int i = 0; i < n; i++) {
          double api = A.at(p, i), aqi = A.at(q, i);
          A.at(p, i) = c * api - s * aqi;
          A.at(q, i) = s * api + c * aqi;
        }
        for (int i = 0; i < n; i++) {
          double vip = V.at(i, p), viq = V.at(i, q);
          V.at(i, p) = c * vip - s * viq;
          V.at(i, q) = s * vip + c * viq;
        }
      }
  }
  w.assign(n, 0.0);
  for (int i = 0; i < n; i++) w[i] = A.at(i, i);
}

static DMat harmonic_basis_t(int L) {
  if (L == 0) { DMat B(1, 1); B.at(0, 0) = 1.0; return B; }
  if (L == 1) { DMat B(3, 3); for (int i = 0; i < 3; i++) B.at(i, i) = 1.0; return B; }
  DMat Delta = laplacian(L);
  DMat Nl = lq_null(Delta);
  int n = Nl.c, d = Nl.r;
  DMat B(n, d);
  for (int i = 0; i < n; i++)
    for (int q = 0; q < d; q++) B.at(i, q) = Nl.at(q, i);
  DMat G = gram(L);
  DMat M = matmul(matmul(transpose(B), G), B);
  std::vector<double> ev;
  DMat V;
  eigh_sym(M, ev, V);
  DMat W(d, d);
  for (int i = 0; i < d; i++)
    for (int j = 0; j < d; j++) {
      double s = 0;
      for (int k = 0; k < d; k++) {
        double lam = ev[k] < 1e-14 ? 1e-14 : ev[k];
        s += V.at(i, k) * V.at(j, k) / std::sqrt(lam);
      }
      W.at(i, j) = s;
    }
  return matmul(B, W);
}

static DMat r2k_lift(int l, int k) {
  int L = l + 2 * k;
  auto ctsl = counts_list(l);
  auto ctsL = counts_list(L);
  DMat M((int)ctsL.size(), (int)ctsl.size());
  for (size_t j = 0; j < ctsl.size(); j++) {
    int a = ctsl[j][0], b = ctsl[j][1], c = ctsl[j][2];
    for (int p = 0; p <= k; p++)
      for (int q = 0; q <= k - p; q++) {
        int r = k - p - q;
        double coef = fact(k) / (fact(p) * fact(q) * fact(r));
        M.at(find_idx(ctsL, a + 2 * p, b + 2 * q, c + 2 * r), (int)j) += coef;
      }
  }
  return M;
}

static DMat solve_mat(DMat G, DMat R) {
  int d = G.r, c = R.c;
  for (int col = 0; col < d; col++) {
    int piv = col;
    for (int r2 = col + 1; r2 < d; r2++)
      if (std::fabs(G.at(r2, col)) > std::fabs(G.at(piv, col))) piv = r2;
    if (piv != col) {
      for (int c2 = 0; c2 < d; c2++) std::swap(G.at(col, c2), G.at(piv, c2));
      for (int c2 = 0; c2 < c; c2++) std::swap(R.at(col, c2), R.at(piv, c2));
    }
    double dv = G.at(col, col);
    for (int r2 = col + 1; r2 < d; r2++) {
      double f = G.at(r2, col) / dv;
      for (int c2 = col; c2 < d; c2++) G.at(r2, c2) -= f * G.at(col, c2);
      for (int c2 = 0; c2 < c; c2++) R.at(r2, c2) -= f * R.at(col, c2);
    }
  }
  for (int col = d - 1; col >= 0; col--)
    for (int c2 = 0; c2 < c; c2++) {
      double s = R.at(col, c2);
      for (int k2 = col + 1; k2 < d; k2++) s -= G.at(col, k2) * R.at(k2, c2);
      R.at(col, c2) = s / G.at(col, col);
    }
  return R;
}

static DMat projector(int L, int l) {
  int k = (L - l) / 2;
  DMat GL = gram(L);
  DMat Bl = harmonic_basis_t(l);
  DMat M = r2k_lift(l, k);
  DMat V = matmul(M, Bl);
  DMat VtGL = matmul(transpose(V), GL);
  DMat G2 = matmul(VtGL, V);
  return solve_mat(G2, VtGL);
}

static void build_cg(int l1, int l2, int l3, double* out) {  // out[m][n][k]
  int L = l1 + l2;
  DMat P = projector(L, l3);
  DMat B1 = harmonic_basis_t(l1), B2 = harmonic_basis_t(l2);
  auto cts1 = counts_list(l1), cts2 = counts_list(l2), ctsL = counts_list(L);
  int m1 = 2 * l1 + 1, m2 = 2 * l2 + 1, m3 = 2 * l3 + 1;
  int DL = (int)ctsL.size();
  std::vector<double> tL(DL);
  for (int a1 = 0; a1 < m1; a1++)
    for (int a2 = 0; a2 < m2; a2++) {
      std::fill(tL.begin(), tL.end(), 0.0);
      for (size_t i = 0; i < cts1.size(); i++)
        for (size_t j = 0; j < cts2.size(); j++) {
          int idx = find_idx(ctsL, cts1[i][0] + cts2[j][0], cts1[i][1] + cts2[j][1],
                             cts1[i][2] + cts2[j][2]);
          tL[idx] += B1.at((int)i, a1) * B2.at((int)j, a2);
        }
      for (int k = 0; k < m3; k++) {
        double s = 0;
        for (int t = 0; t < DL; t++) s += P.at(k, t) * tL[t];
        out[(a1 * m2 + a2) * m3 + k] = s;
      }
    }
}

}  // namespace cgh

// ========================== path tables =====================================
static constexpr int PL1[11]   = {0, 0, 0, 1, 1, 1, 1, 2, 2, 2, 2};
static constexpr int PL2[11]   = {0, 1, 2, 0, 1, 1, 2, 0, 1, 2, 2};
static constexpr int PL3[11]   = {0, 1, 2, 1, 0, 2, 1, 2, 1, 0, 2};
static constexpr int CGOFF[11] = {0, 1, 10, 35, 44, 53, 98, 143, 168, 213, 238};
static constexpr int CGTOT = 363;

struct CGPack { float v[CGTOT]; };  // 1452 B by-value kernarg

static float g_cg_f[CGTOT];
static struct CGInitOnce {
  CGInitOnce() {
    int off = 0;
    for (int p = 0; p < 11; p++) {
      int l1 = PL1[p], l2 = PL2[p], l3 = PL3[p];
      int sz = (2 * l1 + 1) * (2 * l2 + 1) * (2 * l3 + 1);
      std::vector<double> tmp(sz, 0.0);
      cgh::build_cg(l1, l2, l3, tmp.data());
      for (int t = 0; t < sz; t++) g_cg_f[off + t] = (float)tmp[t];
      off += sz;
    }
  }
} g_cg_init_once;

// ============================== device code =================================
#define NBLK 16  // nodes per block (50000 = 3125 * 16 exactly)

typedef __attribute__((ext_vector_type(8))) unsigned short ushort8_t;

static __device__ __forceinline__ float bf2f(unsigned short u) {
  return __uint_as_float((unsigned int)u << 16);
}
static __device__ __forceinline__ unsigned short f2bf(float f) {
  __hip_bfloat16 h = __float2bfloat16(f);
  union { __hip_bfloat16 h; unsigned short u; } cv;
  cv.h = h;
  return cv.u;
}

__global__ __launch_bounds__(256, 3) void harm_tp_kernel(
    const float* __restrict__ x1_0, const float* __restrict__ x1_1,
    const float* __restrict__ x1_2, const float* __restrict__ x2_0,
    const float* __restrict__ x2_1, const float* __restrict__ x2_2,
    const float* __restrict__ w, float* __restrict__ out, int nodes, CGPack cg) {
  // LDS: 18432 + 20480 + 1600 + 9216 + 576 + 1452 = 51756 B -> 3 blocks/CU
  __shared__ __align__(16) unsigned short x2s[NBLK][9][64];  // bf16 [node][comp][mul]
  __shared__ __align__(16) float T2[NBLK][5][64];            // [node][k][j]
  __shared__ float sb[NBLK][5][5];                           // [node][n][k]
  __shared__ __align__(16) unsigned short wls[64][72];       // bf16 w[o][j], pad->72
  __shared__ float x1c[NBLK][9];                             // x1 column i
  __shared__ float cgs[CGTOT];

  const int tid = threadIdx.x;
  const int o = tid & 63;          // output multiplicity on lanes
  const int q = tid >> 6;          // wave id
  const int wr = tid >> 2;         // weight-stage o-row (0..63)
  const int wc = (tid & 3) << 4;   // weight-stage j base (0,16,32,48)
  const int base = blockIdx.x * NBLK;

  // ---- prologue: stage x2 (bf16), cg, x1 column 0; prefetch w[p=0,:,0,:] ----
  for (int t = tid; t < NBLK * 64; t += 256) {
    int b = t >> 6, i2 = t & 63;
    x2s[b][0][i2] = f2bf(x2_0[(size_t)(base + b) * 64 + i2]);
  }
  for (int t = tid; t < NBLK * 192; t += 256) {
    int b = t / 192, r = t % 192, i2 = r / 3, m = r % 3;
    x2s[b][1 + m][i2] = f2bf(x2_1[(size_t)(base + b) * 192 + r]);
  }
  for (int t = tid; t < NBLK * 320; t += 256) {
    int b = t / 320, r = t % 320, i2 = r / 5, m = r % 5;
    x2s[b][4 + m][i2] = f2bf(x2_2[(size_t)(base + b) * 320 + r]);
  }
  for (int t = tid; t < CGTOT; t += 256) cgs[t] = cg.v[t];
  if (tid < NBLK * 9) {
    int b = tid / 9, c = tid % 9;
    float v;
    if (c == 0)      v = x1_0[(size_t)(base + b) * 64];
    else if (c < 4)  v = x1_1[(size_t)(base + b) * 192 + (c - 1)];
    else             v = x1_2[(size_t)(base + b) * 320 + (c - 4)];
    x1c[b][c] = v;
  }
  float4 wv0, wv1, wv2, wv3;  // 16 weights: w[p, wr, i, wc..wc+15]
  {
    const float* wp0 = w + (size_t)wr * 4096 + wc;  // p=0, i=0
    wv0 = *(const float4*)(wp0 + 0);
    wv1 = *(const float4*)(wp0 + 4);
    wv2 = *(const float4*)(wp0 + 8);
    wv3 = *(const float4*)(wp0 + 12);
  }
  __syncthreads();

  float acc[4][9];
#pragma unroll
  for (int bi = 0; bi < 4; bi++)
#pragma unroll
    for (int k = 0; k < 9; k++) acc[bi][k] = 0.f;

#pragma unroll
  for (int p = 0; p < 11; p++) {
    const int l1 = PL1[p], l2v = PL2[p], l3 = PL3[p];
    const int m1 = 2 * l1 + 1, m2v = 2 * l2v + 1, m3 = 2 * l3 + 1;
    const int o1 = l1 * l1, o2 = l2v * l2v, o3 = l3 * l3;
    const int cgo = CGOFF[p];

    for (int i = 0; i < 64; i++) {
      // ---- A: wls store (from prefetched wv*) + sb compute ----
      {
        ushort8_t u0, u1;
        u0[0] = f2bf(wv0.x); u0[1] = f2bf(wv0.y); u0[2] = f2bf(wv0.z); u0[3] = f2bf(wv0.w);
        u0[4] = f2bf(wv1.x); u0[5] = f2bf(wv1.y); u0[6] = f2bf(wv1.z); u0[7] = f2bf(wv1.w);
        u1[0] = f2bf(wv2.x); u1[1] = f2bf(wv2.y); u1[2] = f2bf(wv2.z); u1[3] = f2bf(wv2.w);
        u1[4] = f2bf(wv3.x); u1[5] = f2bf(wv3.y); u1[6] = f2bf(wv3.z); u1[7] = f2bf(wv3.w);
        *(ushort8_t*)&wls[wr][wc] = u0;
        *(ushort8_t*)&wls[wr][wc + 8] = u1;
      }
      const int tasks1 = NBLK * m2v * m3;
      for (int t = tid; t < tasks1; t += 256) {
        int b = t / (m2v * m3), r = t % (m2v * m3), n = r / m3, k = r % m3;
        float s = 0.f;
#pragma unroll
        for (int m = 0; m < m1; m++)
          s += x1c[b][o1 + m] * cgs[cgo + (m * m2v + n) * m3 + k];
        sb[b][n][k] = s;
      }
      __syncthreads();

      // ---- B: T2[b][k][j] = sum_n x2[b,j,n] * sb[b][n][k] ----
      const int tasks2 = NBLK * m3 * 16;
      for (int t = tid; t < tasks2; t += 256) {
        int b = t / (m3 * 16), r = t % (m3 * 16), k = r >> 4, j4 = (r & 15) << 2;
        float4 s = make_float4(0.f, 0.f, 0.f, 0.f);
#pragma unroll
        for (int n = 0; n < m2v; n++) {
          float sv = sb[b][n][k];
          ushort4 xv = *(const ushort4*)&x2s[b][o2 + n][j4];
          s.x += sv * bf2f(xv.x);
          s.y += sv * bf2f(xv.y);
          s.z += sv * bf2f(xv.z);
          s.w += sv * bf2f(xv.w);
        }
        *(float4*)&T2[b][k][j4] = s;
      }
      __syncthreads();

      // ---- C: j-chunked accumulate — NO per-thread 64-float array.
      // 8 weights live at a time in named scalars; T2 reads are wave-uniform
      // LDS broadcasts. Per-thread live state ~90 VGPRs < 168 cap at 3 w/EU.
#pragma unroll
      for (int jc = 0; jc < 8; jc++) {
        const ushort8_t w8 = *(const ushort8_t*)&wls[o][jc * 8];
        const float wf0 = bf2f(w8[0]), wf1 = bf2f(w8[1]);
        const float wf2 = bf2f(w8[2]), wf3 = bf2f(w8[3]);
        const float wf4 = bf2f(w8[4]), wf5 = bf2f(w8[5]);
        const float wf6 = bf2f(w8[6]), wf7 = bf2f(w8[7]);
#pragma unroll
        for (int bi = 0; bi < 4; bi++) {
          const int b = (q << 2) | bi;
#pragma unroll
          for (int k = 0; k < m3; k++) {
            const float4 tv0 = *(const float4*)&T2[b][k][jc * 8];
            const float4 tv1 = *(const float4*)&T2[b][k][jc * 8 + 4];
            const float s0 = wf0 * tv0.x + wf1 * tv0.y + wf2 * tv0.z + wf3 * tv0.w;
            const float s1 = wf4 * tv1.x + wf5 * tv1.y + wf6 * tv1.z + wf7 * tv1.w;
            acc[bi][o3 + k] += s0 + s1;
          }
        }
      }

      // prefetch weight slice + x1 column for next (p,i)
      if (p < 10 || i < 63) {
        const int in = (i < 63) ? i + 1 : 0;
        const int pn = (i < 63) ? p : p + 1;
        const float* wpp = w + (size_t)pn * 262144 + (size_t)wr * 4096 +
                           (size_t)in * 64 + wc;
        wv0 = *(const float4*)(wpp + 0);
        wv1 = *(const float4*)(wpp + 4);
        wv2 = *(const float4*)(wpp + 8);
        wv3 = *(const float4*)(wpp + 12);
        if (tid < NBLK * 9) {
          int b = tid / 9, c = tid % 9;
          float v;
          if (c == 0)      v = x1_0[(size_t)(base + b) * 64 + in];
          else if (c < 4)  v = x1_1[(size_t)(base + b) * 192 + in * 3 + (c - 1)];
          else             v = x1_2[(size_t)(base + b) * 320 + in * 5 + (c - 4)];
          x1c[b][c] = v;
        }
      }
      __syncthreads();
    }
  }

  // ---- epilogue: out shape (N, 64, 9) ----
#pragma unroll
  for (int bi = 0; bi < 4; bi++) {
    const int b = (q << 2) | bi;
    if (base + b < nodes) {
      float* op = out + (size_t)(base + b) * 576 + (size_t)o * 9;
#pragma unroll
      for (int k = 0; k < 9; k++) op[k] = acc[bi][k];
    }
  }
}

// ============================== launch ======================================
extern "C" void kernel_launch(void* const* d_in, const int* in_sizes, int n_in,
                              void* d_out, int out_size, void* d_ws, size_t ws_size,
                              hipStream_t stream) {
  // setup_inputs() dict insertion order is INTERLEAVED:
  //   d_in[0]=x1_l0, d_in[1]=x2_l0, d_in[2]=x1_l1, d_in[3]=x2_l1,
  //   d_in[4]=x1_l2, d_in[5]=x2_l2, d_in[6]=weight
  const float* x1_0 = (const float*)d_in[0];
  const float* x2_0 = (const float*)d_in[1];
  const float* x1_1 = (const float*)d_in[2];
  const float* x2_1 = (const float*)d_in[3];
  const float* x1_2 = (const float*)d_in[4];
  const float* x2_2 = (const float*)d_in[5];
  const float* w    = (const float*)d_in[6];

  const int nodes = in_sizes[0] / 64;  // 50000

  CGPack pack;
  memcpy(pack.v, g_cg_f, sizeof(pack.v));

  harm_tp_kernel<<<(nodes + NBLK - 1) / NBLK, 256, 0, stream>>>(
      x1_0, x1_1, x1_2, x2_0, x2_1, x2_2, w, (float*)d_out, nodes, pack);
}

// Round 2
// 6767.786 us; speedup vs baseline: 160.0194x; 8.0578x over previous
//
#include <hip/hip_runtime.h>
#include <hip/hip_bf16.h>
#include <vector>
#include <array>
#include <cmath>
#include <cstring>

// ============================================================================
// Host-side CG tensor construction (replicates the numpy reference, fp64).
// ============================================================================
namespace cgh {

struct DMat {
  int r = 0, c = 0;
  std::vector<double> a;
  DMat() {}
  DMat(int r_, int c_) : r(r_), c(c_), a((size_t)r_ * c_, 0.0) {}
  double& at(int i, int j) { return a[(size_t)i * c + j]; }
  double at(int i, int j) const { return a[(size_t)i * c + j]; }
};

static std::vector<std::array<int, 3>> counts_list(int L) {
  std::vector<std::array<int, 3>> v;
  for (int a = L; a >= 0; a--)
    for (int b = L - a; b >= 0; b--)
      v.push_back({a, b, L - a - b});
  return v;
}

static double dfact(int n) { double o = 1; for (int k = n; k > 0; k -= 2) o *= k; return o; }
static double gmom(int n) { return (n % 2) ? 0.0 : dfact(n - 1); }
static double fact(int n) { double o = 1; for (int i = 2; i <= n; i++) o *= i; return o; }

static DMat gram(int L) {
  auto cts = counts_list(L);
  int D = (int)cts.size();
  DMat G(D, D);
  for (int i = 0; i < D; i++)
    for (int j = 0; j < D; j++)
      G.at(i, j) = gmom(cts[i][0] + cts[j][0]) * gmom(cts[i][1] + cts[j][1]) *
                   gmom(cts[i][2] + cts[j][2]);
  return G;
}

static int find_idx(const std::vector<std::array<int, 3>>& cts, int a, int b, int c) {
  for (size_t i = 0; i < cts.size(); i++)
    if (cts[i][0] == a && cts[i][1] == b && cts[i][2] == c) return (int)i;
  return -1;
}

static DMat laplacian(int L) {
  auto ctsL = counts_list(L);
  auto ctsM = counts_list(L - 2);
  DMat D((int)ctsM.size(), (int)ctsL.size());
  for (size_t j = 0; j < ctsL.size(); j++) {
    int a = ctsL[j][0], b = ctsL[j][1], c = ctsL[j][2];
    if (a >= 2) D.at(find_idx(ctsM, a - 2, b, c), (int)j) += a * (a - 1);
    if (b >= 2) D.at(find_idx(ctsM, a, b - 2, c), (int)j) += b * (b - 1);
    if (c >= 2) D.at(find_idx(ctsM, a, b, c - 2), (int)j) += c * (c - 1);
  }
  return D;
}

// dgelqf + dorglq: bottom (n-m) rows of Q (= vh[rank:] for full-row-rank A)
static DMat lq_null(DMat A) {
  int m = A.r, n = A.c;
  std::vector<double> tau(m, 0.0);
  for (int i = 0; i < m; i++) {
    double xn2 = 0;
    for (int c2 = i + 1; c2 < n; c2++) xn2 += A.at(i, c2) * A.at(i, c2);
    double alpha = A.at(i, i);
    if (xn2 == 0.0) { tau[i] = 0.0; continue; }
    double nrm = std::sqrt(alpha * alpha + xn2);
    double beta = (alpha >= 0.0) ? -nrm : nrm;
    tau[i] = (beta - alpha) / beta;
    double sc = 1.0 / (alpha - beta);
    for (int c2 = i + 1; c2 < n; c2++) A.at(i, c2) *= sc;
    A.at(i, i) = beta;
    for (int r2 = i + 1; r2 < m; r2++) {
      double w = A.at(r2, i);
      for (int c2 = i + 1; c2 < n; c2++) w += A.at(r2, c2) * A.at(i, c2);
      w *= tau[i];
      A.at(r2, i) -= w;
      for (int c2 = i + 1; c2 < n; c2++) A.at(r2, c2) -= w * A.at(i, c2);
    }
  }
  DMat Q(n, n);
  for (int i = 0; i < n; i++) Q.at(i, i) = 1.0;
  for (int i = 0; i < m; i++) {
    if (tau[i] == 0.0) continue;
    std::vector<double> v(n, 0.0);
    v[i] = 1.0;
    for (int c2 = i + 1; c2 < n; c2++) v[c2] = A.at(i, c2);
    for (int c2 = 0; c2 < n; c2++) {
      double s = 0;
      for (int r2 = i; r2 < n; r2++) s += v[r2] * Q.at(r2, c2);
      s *= tau[i];
      for (int r2 = i; r2 < n; r2++) Q.at(r2, c2) -= v[r2] * s;
    }
  }
  DMat Nl(n - m, n);
  for (int r2 = 0; r2 < n - m; r2++)
    for (int c2 = 0; c2 < n; c2++) Nl.at(r2, c2) = Q.at(m + r2, c2);
  return Nl;
}

static DMat matmul(const DMat& A, const DMat& B) {
  DMat C(A.r, B.c);
  for (int i = 0; i < A.r; i++)
    for (int k = 0; k < A.c; k++) {
      double av = A.at(i, k);
      if (av == 0.0) continue;
      for (int j = 0; j < B.c; j++) C.at(i, j) += av * B.at(k, j);
    }
  return C;
}
static DMat transpose(const DMat& A) {
  DMat T(A.c, A.r);
  for (int i = 0; i < A.r; i++)
    for (int j = 0; j < A.c; j++) T.at(j, i) = A.at(i, j);
  return T;
}

static void eigh_sym(DMat A, std::vector<double>& w, DMat& V) {
  int n = A.r;
  V = DMat(n, n);
  for (int i = 0; i < n; i++) V.at(i, i) = 1.0;
  for (int sweep = 0; sweep < 200; sweep++) {
    double off = 0;
    for (int p = 0; p < n - 1; p++)
      for (int q = p + 1; q < n; q++) off += A.at(p, q) * A.at(p, q);
    if (off < 1e-28) break;
    for (int p = 0; p < n - 1; p++)
      for (int q = p + 1; q < n; q++) {
        double apq = A.at(p, q);
        if (std::fabs(apq) < 1e-300) continue;
        double app = A.at(p, p), aqq = A.at(q, q);
        double th = (aqq - app) / (2.0 * apq);
        double t = (th >= 0) ? 1.0 / (th + std::sqrt(1.0 + th * th))
                             : 1.0 / (th - std::sqrt(1.0 + th * th));
        double c = 1.0 / std::sqrt(1.0 + t * t), s = t * c;
        for (int i = 0; i < n; i++) {
          double aip = A.at(i, p), aiq = A.at(i, q);
          A.at(i, p) = c * aip - s * aiq;
          A.at(i, q) = s * aip + c * aiq;
        }
        for (int i = 0; i < n; i++) {
          double api = A.at(p, i), aqi = A.at(q, i);
          A.at(p, i) = c * api - s * aqi;
          A.at(q, i) = s * api + c * aqi;
        }
        for (int i = 0; i < n; i++) {
          double vip = V.at(i, p), viq = V.at(i, q);
          V.at(i, p) = c * vip - s * viq;
          V.at(i, q) = s * vip + c * viq;
        }
      }
  }
  w.assign(n, 0.0);
  for (int i = 0; i < n; i++) w[i] = A.at(i, i);
}

static DMat harmonic_basis_t(int L) {
  if (L == 0) { DMat B(1, 1); B.at(0, 0) = 1.0; return B; }
  if (L == 1) { DMat B(3, 3); for (int i = 0; i < 3; i++) B.at(i, i) = 1.0; return B; }
  DMat Delta = laplacian(L);
  DMat Nl = lq_null(Delta);
  int n = Nl.c, d = Nl.r;
  DMat B(n, d);
  for (int i = 0; i < n; i++)
    for (int q = 0; q < d; q++) B.at(i, q) = Nl.at(q, i);
  DMat G = gram(L);
  DMat M = matmul(matmul(transpose(B), G), B);
  std::vector<double> ev;
  DMat V;
  eigh_sym(M, ev, V);
  DMat W(d, d);
  for (int i = 0; i < d; i++)
    for (int j = 0; j < d; j++) {
      double s = 0;
      for (int k = 0; k < d; k++) {
        double lam = ev[k] < 1e-14 ? 1e-14 : ev[k];
        s += V.at(i, k) * V.at(j, k) / std::sqrt(lam);
      }
      W.at(i, j) = s;
    }
  return matmul(B, W);
}

static DMat r2k_lift(int l, int k) {
  int L = l + 2 * k;
  auto ctsl = counts_list(l);
  auto ctsL = counts_list(L);
  DMat M((int)ctsL.size(), (int)ctsl.size());
  for (size_t j = 0; j < ctsl.size(); j++) {
    int a = ctsl[j][0], b = ctsl[j][1], c = ctsl[j][2];
    for (int p = 0; p <= k; p++)
      for (int q = 0; q <= k - p; q++) {
        int r = k - p - q;
        double coef = fact(k) / (fact(p) * fact(q) * fact(r));
        M.at(find_idx(ctsL, a + 2 * p, b + 2 * q, c + 2 * r), (int)j) += coef;
      }
  }
  return M;
}

static DMat solve_mat(DMat G, DMat R) {
  int d = G.r, c = R.c;
  for (int col = 0; col < d; col++) {
    int piv = col;
    for (int r2 = col + 1; r2 < d; r2++)
      if (std::fabs(G.at(r2, col)) > std::fabs(G.at(piv, col))) piv = r2;
    if (piv != col) {
      for (int c2 = 0; c2 < d; c2++) std::swap(G.at(col, c2), G.at(piv, c2));
      for (int c2 = 0; c2 < c; c2++) std::swap(R.at(col, c2), R.at(piv, c2));
    }
    double dv = G.at(col, col);
    for (int r2 = col + 1; r2 < d; r2++) {
      double f = G.at(r2, col) / dv;
      for (int c2 = col; c2 < d; c2++) G.at(r2, c2) -= f * G.at(col, c2);
      for (int c2 = 0; c2 < c; c2++) R.at(r2, c2) -= f * R.at(col, c2);
    }
  }
  for (int col = d - 1; col >= 0; col--)
    for (int c2 = 0; c2 < c; c2++) {
      double s = R.at(col, c2);
      for (int k2 = col + 1; k2 < d; k2++) s -= G.at(col, k2) * R.at(k2, c2);
      R.at(col, c2) = s / G.at(col, col);
    }
  return R;
}

static DMat projector(int L, int l) {
  int k = (L - l) / 2;
  DMat GL = gram(L);
  DMat Bl = harmonic_basis_t(l);
  DMat M = r2k_lift(l, k);
  DMat V = matmul(M, Bl);
  DMat VtGL = matmul(transpose(V), GL);
  DMat G2 = matmul(VtGL, V);
  return solve_mat(G2, VtGL);
}

static void build_cg(int l1, int l2, int l3, double* out) {  // out[m][n][k]
  int L = l1 + l2;
  DMat P = projector(L, l3);
  DMat B1 = harmonic_basis_t(l1), B2 = harmonic_basis_t(l2);
  auto cts1 = counts_list(l1), cts2 = counts_list(l2), ctsL = counts_list(L);
  int m1 = 2 * l1 + 1, m2 = 2 * l2 + 1, m3 = 2 * l3 + 1;
  int DL = (int)ctsL.size();
  std::vector<double> tL(DL);
  for (int a1 = 0; a1 < m1; a1++)
    for (int a2 = 0; a2 < m2; a2++) {
      std::fill(tL.begin(), tL.end(), 0.0);
      for (size_t i = 0; i < cts1.size(); i++)
        for (size_t j = 0; j < cts2.size(); j++) {
          int idx = find_idx(ctsL, cts1[i][0] + cts2[j][0], cts1[i][1] + cts2[j][1],
                             cts1[i][2] + cts2[j][2]);
          tL[idx] += B1.at((int)i, a1) * B2.at((int)j, a2);
        }
      for (int k = 0; k < m3; k++) {
        double s = 0;
        for (int t = 0; t < DL; t++) s += P.at(k, t) * tL[t];
        out[(a1 * m2 + a2) * m3 + k] = s;
      }
    }
}

}  // namespace cgh

// ========================== path tables =====================================
static constexpr int PL1[11]   = {0, 0, 0, 1, 1, 1, 1, 2, 2, 2, 2};
static constexpr int PL2[11]   = {0, 1, 2, 0, 1, 1, 2, 0, 1, 2, 2};
static constexpr int PL3[11]   = {0, 1, 2, 1, 0, 2, 1, 2, 1, 0, 2};
static constexpr int CGOFF[11] = {0, 1, 10, 35, 44, 53, 98, 143, 168, 213, 238};
static constexpr int CGTOT = 363;

struct CGPack { float v[CGTOT]; };  // 1452 B by-value kernarg

static float g_cg_f[CGTOT];
static struct CGInitOnce {
  CGInitOnce() {
    int off = 0;
    for (int p = 0; p < 11; p++) {
      int l1 = PL1[p], l2 = PL2[p], l3 = PL3[p];
      int sz = (2 * l1 + 1) * (2 * l2 + 1) * (2 * l3 + 1);
      std::vector<double> tmp(sz, 0.0);
      cgh::build_cg(l1, l2, l3, tmp.data());
      for (int t = 0; t < sz; t++) g_cg_f[off + t] = (float)tmp[t];
      off += sz;
    }
  }
} g_cg_init_once;

// ============================== device code =================================
#define NBLK 16  // nodes per block (50000 = 3125 * 16 exactly)

typedef __attribute__((ext_vector_type(8))) unsigned short ushort8_t;
typedef __attribute__((ext_vector_type(8))) short short8_t;   // MFMA bf16 A/B frag
typedef __attribute__((ext_vector_type(4))) float f32x4_t;    // MFMA C/D frag

static __device__ __forceinline__ float bf2f(unsigned short u) {
  return __uint_as_float((unsigned int)u << 16);
}
static __device__ __forceinline__ unsigned short f2bf(float f) {
  __hip_bfloat16 h = __float2bfloat16(f);
  union { __hip_bfloat16 h; unsigned short u; } cv;
  cv.h = h;
  return cv.u;
}

__global__ __launch_bounds__(256, 3) void harm_tp_kernel(
    const float* __restrict__ x1_0, const float* __restrict__ x1_1,
    const float* __restrict__ x1_2, const float* __restrict__ x2_0,
    const float* __restrict__ x2_1, const float* __restrict__ x2_2,
    const float* __restrict__ w, float* __restrict__ out, int nodes, CGPack cg) {
  // LDS: 18432 + 11520 + 11520 + 9216 + 576 + 1452 = 52716 B -> 3 blocks/CU
  __shared__ __align__(16) unsigned short x2s[NBLK][9][64];  // bf16 [node][comp][mul]
  __shared__ __align__(16) unsigned short T2h[NBLK][5][72];  // bf16 hi [b][k][j] pad->72
  __shared__ __align__(16) unsigned short T2l[NBLK][5][72];  // bf16 lo [b][k][j]
  __shared__ __align__(16) unsigned short wls[64][72];       // bf16 w[o][j], pad->72
  __shared__ float x1c[NBLK][9];                             // x1 column i
  __shared__ float cgs[CGTOT];

  const int tid  = threadIdx.x;
  const int lane = tid & 63;
  const int wid  = tid >> 6;       // wave id = o-tile (16 o's per wave)
  const int lm   = lane & 15;      // A row-in-tile / B col (=b) / D col (=b)
  const int lh   = lane >> 4;      // k-group selector (8 elems each)
  const int wr   = tid >> 2;       // weight-stage o-row (0..63)
  const int wc   = (tid & 3) << 4; // weight-stage j base (0,16,32,48)
  const int base = blockIdx.x * NBLK;

  // ---- prologue: stage x2 (bf16), cg, x1 column 0; prefetch w[p=0,:,0,:] ----
  for (int t = tid; t < NBLK * 64; t += 256) {
    int b = t >> 6, i2 = t & 63;
    x2s[b][0][i2] = f2bf(x2_0[(size_t)(base + b) * 64 + i2]);
  }
  for (int t = tid; t < NBLK * 192; t += 256) {
    int b = t / 192, r = t % 192, i2 = r / 3, m = r % 3;
    x2s[b][1 + m][i2] = f2bf(x2_1[(size_t)(base + b) * 192 + r]);
  }
  for (int t = tid; t < NBLK * 320; t += 256) {
    int b = t / 320, r = t % 320, i2 = r / 5, m = r % 5;
    x2s[b][4 + m][i2] = f2bf(x2_2[(size_t)(base + b) * 320 + r]);
  }
  for (int t = tid; t < CGTOT; t += 256) cgs[t] = cg.v[t];
  if (tid < NBLK * 9) {
    int b = tid / 9, c = tid % 9;
    float v;
    if (c == 0)      v = x1_0[(size_t)(base + b) * 64];
    else if (c < 4)  v = x1_1[(size_t)(base + b) * 192 + (c - 1)];
    else             v = x1_2[(size_t)(base + b) * 320 + (c - 4)];
    x1c[b][c] = v;
  }
  float4 wv0, wv1, wv2, wv3;  // 16 weights: w[p, wr, i, wc..wc+15]
  {
    const float* wp0 = w + (size_t)wr * 4096 + wc;  // p=0, i=0
    wv0 = *(const float4*)(wp0 + 0);
    wv1 = *(const float4*)(wp0 + 4);
    wv2 = *(const float4*)(wp0 + 8);
    wv3 = *(const float4*)(wp0 + 12);
  }
  __syncthreads();

  // accumulators: D[o=wid*16 + lh*4 + r][b=lm][k] ; index = l3*l3 + k (9 total)
  f32x4_t acc[9];
#pragma unroll
  for (int k = 0; k < 9; k++) acc[k] = (f32x4_t){0.f, 0.f, 0.f, 0.f};

#pragma unroll
  for (int p = 0; p < 11; p++) {
    const int l1 = PL1[p], l2v = PL2[p], l3 = PL3[p];
    const int m1 = 2 * l1 + 1, m2v = 2 * l2v + 1, m3 = 2 * l3 + 1;
    const int o1 = l1 * l1, o2 = l2v * l2v, o3 = l3 * l3;
    const int cgo = CGOFF[p];

    for (int i = 0; i < 64; i++) {
      // ---- phase 1: wls store (prefetched regs) + fused sb/T2 hi-lo ----
      {
        ushort8_t u0, u1;
        u0[0] = f2bf(wv0.x); u0[1] = f2bf(wv0.y); u0[2] = f2bf(wv0.z); u0[3] = f2bf(wv0.w);
        u0[4] = f2bf(wv1.x); u0[5] = f2bf(wv1.y); u0[6] = f2bf(wv1.z); u0[7] = f2bf(wv1.w);
        u1[0] = f2bf(wv2.x); u1[1] = f2bf(wv2.y); u1[2] = f2bf(wv2.z); u1[3] = f2bf(wv2.w);
        u1[4] = f2bf(wv3.x); u1[5] = f2bf(wv3.y); u1[6] = f2bf(wv3.z); u1[7] = f2bf(wv3.w);
        *(ushort8_t*)&wls[wr][wc] = u0;
        *(ushort8_t*)&wls[wr][wc + 8] = u1;
      }
      // T2[b][k][j] = sum_n (sum_m x1[b,i,m] cg[m,n,k]) * x2[b,j,n]
      // tasks = NBLK * m3 * 16 = 256*m3 exactly -> m3 per thread, fully static
#pragma unroll
      for (int it = 0; it < m3; it++) {
        const int t = tid + it * 256;
        const int b = t / (m3 * 16);
        const int r = t % (m3 * 16);
        const int k = r >> 4, j4 = (r & 15) << 2;
        float4 s = make_float4(0.f, 0.f, 0.f, 0.f);
#pragma unroll
        for (int n = 0; n < m2v; n++) {
          float coef = 0.f;
#pragma unroll
          for (int m = 0; m < m1; m++)
            coef += x1c[b][o1 + m] * cgs[cgo + (m * m2v + n) * m3 + k];
          ushort4 xv = *(const ushort4*)&x2s[b][o2 + n][j4];
          s.x += coef * bf2f(xv.x);
          s.y += coef * bf2f(xv.y);
          s.z += coef * bf2f(xv.z);
          s.w += coef * bf2f(xv.w);
        }
        ushort4 hi, lo;
        hi.x = f2bf(s.x); lo.x = f2bf(s.x - bf2f(hi.x));
        hi.y = f2bf(s.y); lo.y = f2bf(s.y - bf2f(hi.y));
        hi.z = f2bf(s.z); lo.z = f2bf(s.z - bf2f(hi.z));
        hi.w = f2bf(s.w); lo.w = f2bf(s.w - bf2f(hi.w));
        *(ushort4*)&T2h[b][k][j4] = hi;
        *(ushort4*)&T2l[b][k][j4] = lo;
      }
      __syncthreads();

      // ---- phase 2: prefetch next (p,i); MFMA over j ----
      if (p < 10 || i < 63) {
        const int in = (i < 63) ? i + 1 : 0;
        const int pn = (i < 63) ? p : p + 1;
        const float* wpp = w + (size_t)pn * 262144 + (size_t)wr * 4096 +
                           (size_t)in * 64 + wc;
        wv0 = *(const float4*)(wpp + 0);
        wv1 = *(const float4*)(wpp + 4);
        wv2 = *(const float4*)(wpp + 8);
        wv3 = *(const float4*)(wpp + 12);
        if (tid < NBLK * 9) {
          int b = tid / 9, c = tid % 9;
          float v;
          if (c == 0)      v = x1_0[(size_t)(base + b) * 64 + in];
          else if (c < 4)  v = x1_1[(size_t)(base + b) * 192 + in * 3 + (c - 1)];
          else             v = x1_2[(size_t)(base + b) * 320 + in * 5 + (c - 4)];
          x1c[b][c] = v;
        }
      }
      // A frags: W[o = wid*16 + lm][j = 32*ktile + 8*lh + e]
      const short8_t a0 = *(const short8_t*)&wls[(wid << 4) + lm][8 * lh];
      const short8_t a1 = *(const short8_t*)&wls[(wid << 4) + lm][32 + 8 * lh];
#pragma unroll
      for (int k = 0; k < m3; k++) {
        const short8_t bh0 = *(const short8_t*)&T2h[lm][k][8 * lh];
        const short8_t bh1 = *(const short8_t*)&T2h[lm][k][32 + 8 * lh];
        const short8_t bl0 = *(const short8_t*)&T2l[lm][k][8 * lh];
        const short8_t bl1 = *(const short8_t*)&T2l[lm][k][32 + 8 * lh];
        acc[o3 + k] = __builtin_amdgcn_mfma_f32_16x16x32_bf16(a0, bh0, acc[o3 + k], 0, 0, 0);
        acc[o3 + k] = __builtin_amdgcn_mfma_f32_16x16x32_bf16(a1, bh1, acc[o3 + k], 0, 0, 0);
        acc[o3 + k] = __builtin_amdgcn_mfma_f32_16x16x32_bf16(a0, bl0, acc[o3 + k], 0, 0, 0);
        acc[o3 + k] = __builtin_amdgcn_mfma_f32_16x16x32_bf16(a1, bl1, acc[o3 + k], 0, 0, 0);
      }
      __syncthreads();
    }
  }

  // ---- epilogue: D col = b = lm, row = o-in-tile = lh*4 + r ----
  const int b = base + lm;
  if (b < nodes) {
#pragma unroll
    for (int r = 0; r < 4; r++) {
      const int oo = (wid << 4) + (lh << 2) + r;
      float* op = out + (size_t)b * 576 + (size_t)oo * 9;
#pragma unroll
      for (int k = 0; k < 9; k++) op[k] = acc[k][r];
    }
  }
}

// ============================== launch ======================================
extern "C" void kernel_launch(void* const* d_in, const int* in_sizes, int n_in,
                              void* d_out, int out_size, void* d_ws, size_t ws_size,
                              hipStream_t stream) {
  // setup_inputs() dict insertion order is INTERLEAVED:
  //   d_in[0]=x1_l0, d_in[1]=x2_l0, d_in[2]=x1_l1, d_in[3]=x2_l1,
  //   d_in[4]=x1_l2, d_in[5]=x2_l2, d_in[6]=weight
  const float* x1_0 = (const float*)d_in[0];
  const float* x2_0 = (const float*)d_in[1];
  const float* x1_1 = (const float*)d_in[2];
  const float* x2_1 = (const float*)d_in[3];
  const float* x1_2 = (const float*)d_in[4];
  const float* x2_2 = (const float*)d_in[5];
  const float* w    = (const float*)d_in[6];

  const int nodes = in_sizes[0] / 64;  // 50000

  CGPack pack;
  memcpy(pack.v, g_cg_f, sizeof(pack.v));

  harm_tp_kernel<<<(nodes + NBLK - 1) / NBLK, 256, 0, stream>>>(
      x1_0, x1_1, x1_2, x2_0, x2_1, x2_2, w, (float*)d_out, nodes, pack);
}

// Round 3
// 4811.744 us; speedup vs baseline: 225.0695x; 1.4065x over previous
//
#include <hip/hip_runtime.h>
#include <hip/hip_bf16.h>
#include <vector>
#include <array>
#include <cmath>
#include <cstring>

// ============================================================================
// Host-side CG tensor construction (replicates the numpy reference, fp64).
// ============================================================================
namespace cgh {

struct DMat {
  int r = 0, c = 0;
  std::vector<double> a;
  DMat() {}
  DMat(int r_, int c_) : r(r_), c(c_), a((size_t)r_ * c_, 0.0) {}
  double& at(int i, int j) { return a[(size_t)i * c + j]; }
  double at(int i, int j) const { return a[(size_t)i * c + j]; }
};

static std::vector<std::array<int, 3>> counts_list(int L) {
  std::vector<std::array<int, 3>> v;
  for (int a = L; a >= 0; a--)
    for (int b = L - a; b >= 0; b--)
      v.push_back({a, b, L - a - b});
  return v;
}

static double dfact(int n) { double o = 1; for (int k = n; k > 0; k -= 2) o *= k; return o; }
static double gmom(int n) { return (n % 2) ? 0.0 : dfact(n - 1); }
static double fact(int n) { double o = 1; for (int i = 2; i <= n; i++) o *= i; return o; }

static DMat gram(int L) {
  auto cts = counts_list(L);
  int D = (int)cts.size();
  DMat G(D, D);
  for (int i = 0; i < D; i++)
    for (int j = 0; j < D; j++)
      G.at(i, j) = gmom(cts[i][0] + cts[j][0]) * gmom(cts[i][1] + cts[j][1]) *
                   gmom(cts[i][2] + cts[j][2]);
  return G;
}

static int find_idx(const std::vector<std::array<int, 3>>& cts, int a, int b, int c) {
  for (size_t i = 0; i < cts.size(); i++)
    if (cts[i][0] == a && cts[i][1] == b && cts[i][2] == c) return (int)i;
  return -1;
}

static DMat laplacian(int L) {
  auto ctsL = counts_list(L);
  auto ctsM = counts_list(L - 2);
  DMat D((int)ctsM.size(), (int)ctsL.size());
  for (size_t j = 0; j < ctsL.size(); j++) {
    int a = ctsL[j][0], b = ctsL[j][1], c = ctsL[j][2];
    if (a >= 2) D.at(find_idx(ctsM, a - 2, b, c), (int)j) += a * (a - 1);
    if (b >= 2) D.at(find_idx(ctsM, a, b - 2, c), (int)j) += b * (b - 1);
    if (c >= 2) D.at(find_idx(ctsM, a, b, c - 2), (int)j) += c * (c - 1);
  }
  return D;
}

// dgelqf + dorglq: bottom (n-m) rows of Q (= vh[rank:] for full-row-rank A)
static DMat lq_null(DMat A) {
  int m = A.r, n = A.c;
  std::vector<double> tau(m, 0.0);
  for (int i = 0; i < m; i++) {
    double xn2 = 0;
    for (int c2 = i + 1; c2 < n; c2++) xn2 += A.at(i, c2) * A.at(i, c2);
    double alpha = A.at(i, i);
    if (xn2 == 0.0) { tau[i] = 0.0; continue; }
    double nrm = std::sqrt(alpha * alpha + xn2);
    double beta = (alpha >= 0.0) ? -nrm : nrm;
    tau[i] = (beta - alpha) / beta;
    double sc = 1.0 / (alpha - beta);
    for (int c2 = i + 1; c2 < n; c2++) A.at(i, c2) *= sc;
    A.at(i, i) = beta;
    for (int r2 = i + 1; r2 < m; r2++) {
      double w = A.at(r2, i);
      for (int c2 = i + 1; c2 < n; c2++) w += A.at(r2, c2) * A.at(i, c2);
      w *= tau[i];
      A.at(r2, i) -= w;
      for (int c2 = i + 1; c2 < n; c2++) A.at(r2, c2) -= w * A.at(i, c2);
    }
  }
  DMat Q(n, n);
  for (int i = 0; i < n; i++) Q.at(i, i) = 1.0;
  for (int i = 0; i < m; i++) {
    if (tau[i] == 0.0) continue;
    std::vector<double> v(n, 0.0);
    v[i] = 1.0;
    for (int c2 = i + 1; c2 < n; c2++) v[c2] = A.at(i, c2);
    for (int c2 = 0; c2 < n; c2++) {
      double s = 0;
      for (int r2 = i; r2 < n; r2++) s += v[r2] * Q.at(r2, c2);
      s *= tau[i];
      for (int r2 = i; r2 < n; r2++) Q.at(r2, c2) -= v[r2] * s;
    }
  }
  DMat Nl(n - m, n);
  for (int r2 = 0; r2 < n - m; r2++)
    for (int c2 = 0; c2 < n; c2++) Nl.at(r2, c2) = Q.at(m + r2, c2);
  return Nl;
}

static DMat matmul(const DMat& A, const DMat& B) {
  DMat C(A.r, B.c);
  for (int i = 0; i < A.r; i++)
    for (int k = 0; k < A.c; k++) {
      double av = A.at(i, k);
      if (av == 0.0) continue;
      for (int j = 0; j < B.c; j++) C.at(i, j) += av * B.at(k, j);
    }
  return C;
}
static DMat transpose(const DMat& A) {
  DMat T(A.c, A.r);
  for (int i = 0; i < A.r; i++)
    for (int j = 0; j < A.c; j++) T.at(j, i) = A.at(i, j);
  return T;
}

static void eigh_sym(DMat A, std::vector<double>& w, DMat& V) {
  int n = A.r;
  V = DMat(n, n);
  for (int i = 0; i < n; i++) V.at(i, i) = 1.0;
  for (int sweep = 0; sweep < 200; sweep++) {
    double off = 0;
    for (int p = 0; p < n - 1; p++)
      for (int q = p + 1; q < n; q++) off += A.at(p, q) * A.at(p, q);
    if (off < 1e-28) break;
    for (int p = 0; p < n - 1; p++)
      for (int q = p + 1; q < n; q++) {
        double apq = A.at(p, q);
        if (std::fabs(apq) < 1e-300) continue;
        double app = A.at(p, p), aqq = A.at(q, q);
        double th = (aqq - app) / (2.0 * apq);
        double t = (th >= 0) ? 1.0 / (th + std::sqrt(1.0 + th * th))
                             : 1.0 / (th - std::sqrt(1.0 + th * th));
        double c = 1.0 / std::sqrt(1.0 + t * t), s = t * c;
        for (int i = 0; i < n; i++) {
          double aip = A.at(i, p), aiq = A.at(i, q);
          A.at(i, p) = c * aip - s * aiq;
          A.at(i, q) = s * aip + c * aiq;
        }
        for (int i = 0; i < n; i++) {
          double api = A.at(p, i), aqi = A.at(q, i);
          A.at(p, i) = c * api - s * aqi;
          A.at(q, i) = s * api + c * aqi;
        }
        for (int i = 0; i < n; i++) {
          double vip = V.at(i, p), viq = V.at(i, q);
          V.at(i, p) = c * vip - s * viq;
          V.at(i, q) = s * vip + c * viq;
        }
      }
  }
  w.assign(n, 0.0);
  for (int i = 0; i < n; i++) w[i] = A.at(i, i);
}

static DMat harmonic_basis_t(int L) {
  if (L == 0) { DMat B(1, 1); B.at(0, 0) = 1.0; return B; }
  if (L == 1) { DMat B(3, 3); for (int i = 0; i < 3; i++) B.at(i, i) = 1.0; return B; }
  DMat Delta = laplacian(L);
  DMat Nl = lq_null(Delta);
  int n = Nl.c, d = Nl.r;
  DMat B(n, d);
  for (int i = 0; i < n; i++)
    for (int q = 0; q < d; q++) B.at(i, q) = Nl.at(q, i);
  DMat G = gram(L);
  DMat M = matmul(matmul(transpose(B), G), B);
  std::vector<double> ev;
  DMat V;
  eigh_sym(M, ev, V);
  DMat W(d, d);
  for (int i = 0; i < d; i++)
    for (int j = 0; j < d; j++) {
      double s = 0;
      for (int k = 0; k < d; k++) {
        double lam = ev[k] < 1e-14 ? 1e-14 : ev[k];
        s += V.at(i, k) * V.at(j, k) / std::sqrt(lam);
      }
      W.at(i, j) = s;
    }
  return matmul(B, W);
}

static DMat r2k_lift(int l, int k) {
  int L = l + 2 * k;
  auto ctsl = counts_list(l);
  auto ctsL = counts_list(L);
  DMat M((int)ctsL.size(), (int)ctsl.size());
  for (size_t j = 0; j < ctsl.size(); j++) {
    int a = ctsl[j][0], b = ctsl[j][1], c = ctsl[j][2];
    for (int p = 0; p <= k; p++)
      for (int q = 0; q <= k - p; q++) {
        int r = k - p - q;
        double coef = fact(k) / (fact(p) * fact(q) * fact(r));
        M.at(find_idx(ctsL, a + 2 * p, b + 2 * q, c + 2 * r), (int)j) += coef;
      }
  }
  return M;
}

static DMat solve_mat(DMat G, DMat R) {
  int d = G.r, c = R.c;
  for (int col = 0; col < d; col++) {
    int piv = col;
    for (int r2 = col + 1; r2 < d; r2++)
      if (std::fabs(G.at(r2, col)) > std::fabs(G.at(piv, col))) piv = r2;
    if (piv != col) {
      for (int c2 = 0; c2 < d; c2++) std::swap(G.at(col, c2), G.at(piv, c2));
      for (int c2 = 0; c2 < c; c2++) std::swap(R.at(col, c2), R.at(piv, c2));
    }
    double dv = G.at(col, col);
    for (int r2 = col + 1; r2 < d; r2++) {
      double f = G.at(r2, col) / dv;
      for (int c2 = col; c2 < d; c2++) G.at(r2, c2) -= f * G.at(col, c2);
      for (int c2 = 0; c2 < c; c2++) R.at(r2, c2) -= f * R.at(col, c2);
    }
  }
  for (int col = d - 1; col >= 0; col--)
    for (int c2 = 0; c2 < c; c2++) {
      double s = R.at(col, c2);
      for (int k2 = col + 1; k2 < d; k2++) s -= G.at(col, k2) * R.at(k2, c2);
      R.at(col, c2) = s / G.at(col, col);
    }
  return R;
}

static DMat projector(int L, int l) {
  int k = (L - l) / 2;
  DMat GL = gram(L);
  DMat Bl = harmonic_basis_t(l);
  DMat M = r2k_lift(l, k);
  DMat V = matmul(M, Bl);
  DMat VtGL = matmul(transpose(V), GL);
  DMat G2 = matmul(VtGL, V);
  return solve_mat(G2, VtGL);
}

static void build_cg(int l1, int l2, int l3, double* out) {  // out[m][n][k]
  int L = l1 + l2;
  DMat P = projector(L, l3);
  DMat B1 = harmonic_basis_t(l1), B2 = harmonic_basis_t(l2);
  auto cts1 = counts_list(l1), cts2 = counts_list(l2), ctsL = counts_list(L);
  int m1 = 2 * l1 + 1, m2 = 2 * l2 + 1, m3 = 2 * l3 + 1;
  int DL = (int)ctsL.size();
  std::vector<double> tL(DL);
  for (int a1 = 0; a1 < m1; a1++)
    for (int a2 = 0; a2 < m2; a2++) {
      std::fill(tL.begin(), tL.end(), 0.0);
      for (size_t i = 0; i < cts1.size(); i++)
        for (size_t j = 0; j < cts2.size(); j++) {
          int idx = find_idx(ctsL, cts1[i][0] + cts2[j][0], cts1[i][1] + cts2[j][1],
                             cts1[i][2] + cts2[j][2]);
          tL[idx] += B1.at((int)i, a1) * B2.at((int)j, a2);
        }
      for (int k = 0; k < m3; k++) {
        double s = 0;
        for (int t = 0; t < DL; t++) s += P.at(k, t) * tL[t];
        out[(a1 * m2 + a2) * m3 + k] = s;
      }
    }
}

}  // namespace cgh

// ========================== path tables =====================================
static constexpr int kPL1[11]  = {0, 0, 0, 1, 1, 1, 1, 2, 2, 2, 2};
static constexpr int kPL2[11]  = {0, 1, 2, 0, 1, 1, 2, 0, 1, 2, 2};
static constexpr int kPL3[11]  = {0, 1, 2, 1, 0, 2, 1, 2, 1, 0, 2};
static constexpr int kCGO[11]  = {0, 1, 10, 35, 44, 53, 98, 143, 168, 213, 238};
static constexpr int CGTOT = 363;

// cg2: k-major repack — cg2[CGO[p] + k*(m1*m2) + m*m2 + n] = cg[m][n][k]
static float g_cg2[CGTOT];
static struct CGInitOnce {
  CGInitOnce() {
    for (int p = 0; p < 11; p++) {
      int l1 = kPL1[p], l2 = kPL2[p], l3 = kPL3[p];
      int m1 = 2 * l1 + 1, m2 = 2 * l2 + 1, m3 = 2 * l3 + 1;
      std::vector<double> tmp((size_t)m1 * m2 * m3, 0.0);
      cgh::build_cg(l1, l2, l3, tmp.data());
      for (int k = 0; k < m3; k++)
        for (int m = 0; m < m1; m++)
          for (int n = 0; n < m2; n++)
            g_cg2[kCGO[p] + k * m1 * m2 + m * m2 + n] =
                (float)tmp[(size_t)(m * m2 + n) * m3 + k];
    }
  }
} g_cg_init_once;

// ============================== device code =================================
#define NBLK 16  // nodes per block (50000 = 3125 * 16 exactly)

typedef __attribute__((ext_vector_type(8))) unsigned short ushort8_t;
typedef __attribute__((ext_vector_type(8))) short short8_t;   // MFMA bf16 A/B frag
typedef __attribute__((ext_vector_type(4))) float f32x4_t;    // MFMA C/D frag

static __device__ __forceinline__ float bf2f(unsigned short u) {
  return __uint_as_float((unsigned int)u << 16);
}
static __device__ __forceinline__ unsigned short f2bf(float f) {
  __hip_bfloat16 h = __float2bfloat16(f);
  union { __hip_bfloat16 h; unsigned short u; } cv;
  cv.h = h;
  return cv.u;
}

// sb[b][k][n] = sum_m x1[b, in, m] * cg[m][n][k] — computed by 16*M3 threads,
// reading x1 + repacked cg straight from global (L1/L2-hot). Runs inside
// phase 2 (latency hidden under MFMA); single-buffered: writers and the
// phase-1 readers are always separated by a barrier.
template <int L1, int L2, int L3, int CGO>
static __device__ __forceinline__ void sb_stage(
    int tid, int base, int in, const float* __restrict__ x1_0,
    const float* __restrict__ x1_1, const float* __restrict__ x1_2,
    const float* __restrict__ cg2, float (*sb)[5][8]) {
  constexpr int M1 = 2 * L1 + 1, M2 = 2 * L2 + 1, M3 = 2 * L3 + 1;
  if (tid < 16 * M3) {
    const int b = tid / M3, k = tid - b * M3;
    const float* xp;
    if constexpr (L1 == 0) xp = x1_0 + (size_t)(base + b) * 64 + in;
    else if constexpr (L1 == 1) xp = x1_1 + (size_t)(base + b) * 192 + (size_t)in * 3;
    else xp = x1_2 + (size_t)(base + b) * 320 + (size_t)in * 5;
    float x1r[M1];
#pragma unroll
    for (int m = 0; m < M1; m++) x1r[m] = xp[m];
    const float* cp = cg2 + CGO + k * (M1 * M2);
#pragma unroll
    for (int n = 0; n < M2; n++) {
      float s = 0.f;
#pragma unroll
      for (int m = 0; m < M1; m++) s = fmaf(x1r[m], cp[m * M2 + n], s);
      sb[b][k][n] = s;
    }
  }
}

template <int P>
static __device__ __forceinline__ void run_path(
    int tid, int base, const float* __restrict__ x1_0,
    const float* __restrict__ x1_1, const float* __restrict__ x1_2,
    const float* __restrict__ w, const float* __restrict__ cg2,
    unsigned short (*x2s)[9][64], unsigned short (*T2h)[5][72],
    unsigned short (*T2l)[5][72], unsigned short (*wls)[72],
    float (*sb)[5][8], float4& wv0, float4& wv1, float4& wv2, float4& wv3,
    f32x4_t* acc) {
  constexpr int L1 = kPL1[P], L2 = kPL2[P], L3 = kPL3[P];
  constexpr int M2 = 2 * L2 + 1, M3 = 2 * L3 + 1;
  constexpr int O2 = L2 * L2, O3 = L3 * L3;

  const int lane = tid & 63;
  const int wid = tid >> 6;
  const int lm = lane & 15;
  const int lh = lane >> 4;
  const int wr = tid >> 2;
  const int wc = (tid & 3) << 4;
  const int bb = tid >> 4;        // phase-1 node
  const int j4 = (tid & 15) << 2; // phase-1 j quad

  for (int i = 0; i < 64; ++i) {
    // ---- phase 1: wls store (prefetched regs) + T2 compute (per-(b,j4)) ----
    {
      ushort8_t u0, u1;
      u0[0] = f2bf(wv0.x); u0[1] = f2bf(wv0.y); u0[2] = f2bf(wv0.z); u0[3] = f2bf(wv0.w);
      u0[4] = f2bf(wv1.x); u0[5] = f2bf(wv1.y); u0[6] = f2bf(wv1.z); u0[7] = f2bf(wv1.w);
      u1[0] = f2bf(wv2.x); u1[1] = f2bf(wv2.y); u1[2] = f2bf(wv2.z); u1[3] = f2bf(wv2.w);
      u1[4] = f2bf(wv3.x); u1[5] = f2bf(wv3.y); u1[6] = f2bf(wv3.z); u1[7] = f2bf(wv3.w);
      *(ushort8_t*)&wls[wr][wc] = u0;
      *(ushort8_t*)&wls[wr][wc + 8] = u1;
    }
    {
      // x2 quad per n, read+converted ONCE (not per-k)
      float xf[M2][4];
#pragma unroll
      for (int n = 0; n < M2; n++) {
        ushort4 xv = *(const ushort4*)&x2s[bb][O2 + n][j4];
        xf[n][0] = bf2f(xv.x); xf[n][1] = bf2f(xv.y);
        xf[n][2] = bf2f(xv.z); xf[n][3] = bf2f(xv.w);
      }
#pragma unroll
      for (int k = 0; k < M3; k++) {
        const float4 cv = *(const float4*)&sb[bb][k][0];
        float cvn[5];
        cvn[0] = cv.x; cvn[1] = cv.y; cvn[2] = cv.z; cvn[3] = cv.w;
        cvn[4] = (M2 == 5) ? sb[bb][k][4] : 0.f;
        float s0 = 0.f, s1 = 0.f, s2 = 0.f, s3 = 0.f;
#pragma unroll
        for (int n = 0; n < M2; n++) {
          s0 = fmaf(cvn[n], xf[n][0], s0);
          s1 = fmaf(cvn[n], xf[n][1], s1);
          s2 = fmaf(cvn[n], xf[n][2], s2);
          s3 = fmaf(cvn[n], xf[n][3], s3);
        }
        ushort4 hi, lo;
        hi.x = f2bf(s0); lo.x = f2bf(s0 - bf2f(hi.x));
        hi.y = f2bf(s1); lo.y = f2bf(s1 - bf2f(hi.y));
        hi.z = f2bf(s2); lo.z = f2bf(s2 - bf2f(hi.z));
        hi.w = f2bf(s3); lo.w = f2bf(s3 - bf2f(hi.w));
        *(ushort4*)&T2h[bb][k][j4] = hi;
        *(ushort4*)&T2l[bb][k][j4] = lo;
      }
    }
    __syncthreads();

    // ---- phase 2: sb for next step (global loads hide under MFMA);
    //      w prefetch; MFMA over j ----
    if (i < 63) {
      sb_stage<L1, L2, L3, kCGO[P]>(tid, base, i + 1, x1_0, x1_1, x1_2, cg2, sb);
    } else if constexpr (P < 10) {
      sb_stage<kPL1[P + 1], kPL2[P + 1], kPL3[P + 1], kCGO[P + 1]>(
          tid, base, 0, x1_0, x1_1, x1_2, cg2, sb);
    }
    if (P < 10 || i < 63) {
      const int in_ = (i < 63) ? i + 1 : 0;
      const int pn = (i < 63) ? P : P + 1;
      const float* wpp = w + (size_t)pn * 262144 + (size_t)wr * 4096 +
                         (size_t)in_ * 64 + wc;
      wv0 = *(const float4*)(wpp + 0);
      wv1 = *(const float4*)(wpp + 4);
      wv2 = *(const float4*)(wpp + 8);
      wv3 = *(const float4*)(wpp + 12);
    }
    // A frags: W[o = wid*16 + lm][j = 32*half + 8*lh + e]
    const short8_t a0 = *(const short8_t*)&wls[(wid << 4) + lm][8 * lh];
    const short8_t a1 = *(const short8_t*)&wls[(wid << 4) + lm][32 + 8 * lh];
#pragma unroll
    for (int k = 0; k < M3; k++) {
      const short8_t bh0 = *(const short8_t*)&T2h[lm][k][8 * lh];
      const short8_t bh1 = *(const short8_t*)&T2h[lm][k][32 + 8 * lh];
      const short8_t bl0 = *(const short8_t*)&T2l[lm][k][8 * lh];
      const short8_t bl1 = *(const short8_t*)&T2l[lm][k][32 + 8 * lh];
      acc[O3 + k] = __builtin_amdgcn_mfma_f32_16x16x32_bf16(a0, bh0, acc[O3 + k], 0, 0, 0);
      acc[O3 + k] = __builtin_amdgcn_mfma_f32_16x16x32_bf16(a1, bh1, acc[O3 + k], 0, 0, 0);
      acc[O3 + k] = __builtin_amdgcn_mfma_f32_16x16x32_bf16(a0, bl0, acc[O3 + k], 0, 0, 0);
      acc[O3 + k] = __builtin_amdgcn_mfma_f32_16x16x32_bf16(a1, bl1, acc[O3 + k], 0, 0, 0);
    }
    __syncthreads();
  }
}

__global__ __launch_bounds__(256, 3) void harm_tp_kernel(
    const float* __restrict__ x1_0, const float* __restrict__ x1_1,
    const float* __restrict__ x1_2, const float* __restrict__ x2_0,
    const float* __restrict__ x2_1, const float* __restrict__ x2_2,
    const float* __restrict__ w, const float* __restrict__ cg2,
    float* __restrict__ out, int nodes) {
  // LDS: 18432 + 11520 + 11520 + 9216 + 2560 = 53248 B -> 3 blocks/CU (159744 <= 160K)
  __shared__ __align__(16) unsigned short x2s[NBLK][9][64];  // bf16 [node][comp][mul]
  __shared__ __align__(16) unsigned short T2h[NBLK][5][72];  // bf16 hi [b][k][j] pad->72
  __shared__ __align__(16) unsigned short T2l[NBLK][5][72];  // bf16 lo [b][k][j]
  __shared__ __align__(16) unsigned short wls[64][72];       // bf16 w[o][j], pad->72
  __shared__ __align__(16) float sb[NBLK][5][8];             // coef [b][k][n(pad 8)]

  const int tid = threadIdx.x;
  const int base = blockIdx.x * NBLK;

  // ---- prologue: stage x2 (bf16); sb for (p0,i0); prefetch w[p=0,:,0,:] ----
  for (int t = tid; t < NBLK * 64; t += 256) {
    int b = t >> 6, i2 = t & 63;
    x2s[b][0][i2] = f2bf(x2_0[(size_t)(base + b) * 64 + i2]);
  }
  for (int t = tid; t < NBLK * 192; t += 256) {
    int b = t / 192, r = t % 192, i2 = r / 3, m = r % 3;
    x2s[b][1 + m][i2] = f2bf(x2_1[(size_t)(base + b) * 192 + r]);
  }
  for (int t = tid; t < NBLK * 320; t += 256) {
    int b = t / 320, r = t % 320, i2 = r / 5, m = r % 5;
    x2s[b][4 + m][i2] = f2bf(x2_2[(size_t)(base + b) * 320 + r]);
  }
  sb_stage<0, 0, 0, 0>(tid, base, 0, x1_0, x1_1, x1_2, cg2, sb);
  float4 wv0, wv1, wv2, wv3;  // 16 weights: w[p, wr, i, wc..wc+15]
  {
    const float* wp0 = w + (size_t)(tid >> 2) * 4096 + ((tid & 3) << 4);  // p=0, i=0
    wv0 = *(const float4*)(wp0 + 0);
    wv1 = *(const float4*)(wp0 + 4);
    wv2 = *(const float4*)(wp0 + 8);
    wv3 = *(const float4*)(wp0 + 12);
  }
  __syncthreads();

  // accumulators: D[o=wid*16 + lh*4 + r][b=lm][k] ; index = l3*l3 + k (9 total)
  f32x4_t acc[9];
#pragma unroll
  for (int k = 0; k < 9; k++) acc[k] = (f32x4_t){0.f, 0.f, 0.f, 0.f};

#define RUNP(P)                                                               \
  run_path<P>(tid, base, x1_0, x1_1, x1_2, w, cg2, x2s, T2h, T2l, wls, sb,    \
              wv0, wv1, wv2, wv3, acc);
  RUNP(0) RUNP(1) RUNP(2) RUNP(3) RUNP(4) RUNP(5)
  RUNP(6) RUNP(7) RUNP(8) RUNP(9) RUNP(10)
#undef RUNP

  // ---- epilogue: D col = b = lane&15, row = o-in-tile = (lane>>4)*4 + r ----
  const int lane = tid & 63;
  const int wid = tid >> 6;
  const int lm = lane & 15;
  const int lh = lane >> 4;
  const int b = base + lm;
  if (b < nodes) {
#pragma unroll
    for (int r = 0; r < 4; r++) {
      const int oo = (wid << 4) + (lh << 2) + r;
      float* op = out + (size_t)b * 576 + (size_t)oo * 9;
#pragma unroll
      for (int k = 0; k < 9; k++) op[k] = acc[k][r];
    }
  }
}

// ============================== launch ======================================
extern "C" void kernel_launch(void* const* d_in, const int* in_sizes, int n_in,
                              void* d_out, int out_size, void* d_ws, size_t ws_size,
                              hipStream_t stream) {
  // setup_inputs() dict insertion order is INTERLEAVED:
  //   d_in[0]=x1_l0, d_in[1]=x2_l0, d_in[2]=x1_l1, d_in[3]=x2_l1,
  //   d_in[4]=x1_l2, d_in[5]=x2_l2, d_in[6]=weight
  const float* x1_0 = (const float*)d_in[0];
  const float* x2_0 = (const float*)d_in[1];
  const float* x1_1 = (const float*)d_in[2];
  const float* x2_1 = (const float*)d_in[3];
  const float* x1_2 = (const float*)d_in[4];
  const float* x2_2 = (const float*)d_in[5];
  const float* w    = (const float*)d_in[6];

  const int nodes = in_sizes[0] / 64;  // 50000

  // repacked CG table -> workspace (1452 B; ws_size is comfortably larger)
  hipMemcpyAsync(d_ws, g_cg2, sizeof(g_cg2), hipMemcpyHostToDevice, stream);

  harm_tp_kernel<<<(nodes + NBLK - 1) / NBLK, 256, 0, stream>>>(
      x1_0, x1_1, x1_2, x2_0, x2_1, x2_2, w, (const float*)d_ws, (float*)d_out,
      nodes);
}